// Round 7
// baseline (131491.577 us; speedup 1.0000x reference)
//
#include <hip/hip_runtime.h>
#include <hip/hip_bf16.h>
#include <stdint.h>

// Problem constants: H=1024, IN=1024, L=8, T=2048, OUT=1024.
// Reference quirk: EVERY layer consumes raw x_t, ONE (h,c) pair threads through
// all L*T = 16384 serial cell steps. Output = c_final @ W_out^T + b_out.
#define TSEQ 2048
#define NLAY 8

// ---- bf16 helpers (round-to-nearest-even pack, bit-shift unpack) ----
static __device__ __forceinline__ uint32_t f2bf(float f) {
  uint32_t u = __float_as_uint(f);
  return (u + 0x7FFFu + ((u >> 16) & 1u)) >> 16;
}
static __device__ __forceinline__ float bflo(uint32_t w) { return __uint_as_float(w << 16); }
static __device__ __forceinline__ float bfhi(uint32_t w) { return __uint_as_float(w & 0xFFFF0000u); }

// =====================================================================
// Kernel B: xproj = x @ W_ih^T + b_ih + b_hh  for all (t, l) — parallel GEMM
//   (unchanged from R0 — correctness proven, ~3 ms, not the critical path)
// =====================================================================
__global__ __launch_bounds__(256) void kxproj(const float* __restrict__ x,
                                              const float* __restrict__ Wih,
                                              const float* __restrict__ bih,
                                              const float* __restrict__ bhh,
                                              uint16_t* __restrict__ xp) {
  __shared__ float xs[64][65];   // [t][k] tile (+1 pad: bank-conflict-free)
  __shared__ float wsm[64][65];  // [n][k] tile
  const int tid = threadIdx.x;
  const int tb = blockIdx.x << 6;  // t base (grid.x = 32)
  const int nb = blockIdx.y << 6;  // n base (grid.y = 512)
  const int lr = tid >> 4;         // load row 0..15
  const int lc = (tid & 15) << 2;  // load col group
  const int ty = tid >> 4;         // compute: 16x16 threads, 4x4 outputs each
  const int tx = tid & 15;
  float acc[4][4] = {};
  for (int kk = 0; kk < 1024; kk += 64) {
    __syncthreads();  // protect prior iteration's LDS reads
#pragma unroll
    for (int r4 = 0; r4 < 4; ++r4) {
      const int row = lr + (r4 << 4);
      const float4 xv4 = *(const float4*)&x[(size_t)(tb + row) * 1024 + kk + lc];
      const float4 wv4 = *(const float4*)&Wih[(size_t)(nb + row) * 1024 + kk + lc];
      xs[row][lc + 0] = xv4.x; xs[row][lc + 1] = xv4.y;
      xs[row][lc + 2] = xv4.z; xs[row][lc + 3] = xv4.w;
      wsm[row][lc + 0] = wv4.x; wsm[row][lc + 1] = wv4.y;
      wsm[row][lc + 2] = wv4.z; wsm[row][lc + 3] = wv4.w;
    }
    __syncthreads();
#pragma unroll 4
    for (int k = 0; k < 64; ++k) {
      float xv[4], wv[4];
#pragma unroll
      for (int i = 0; i < 4; ++i) xv[i] = xs[(ty << 2) + i][k];
#pragma unroll
      for (int j = 0; j < 4; ++j) wv[j] = wsm[(tx << 2) + j][k];
#pragma unroll
      for (int i = 0; i < 4; ++i)
#pragma unroll
        for (int j = 0; j < 4; ++j) acc[i][j] += xv[i] * wv[j];
    }
  }
#pragma unroll
  for (int i = 0; i < 4; ++i) {
    const int t = tb + (ty << 2) + i;
#pragma unroll
    for (int j = 0; j < 4; ++j) {
      const int n = nb + (tx << 2) + j;
      const float v = acc[i][j] + bih[n] + bhh[n];
      const int l = n >> 12;
      const int g = (n >> 10) & 3;  // 0=i 1=f 2=g 3=o (PyTorch row order)
      const int u = n & 1023;
      xp[(size_t)(u >> 2) * (TSEQ * 128) + (size_t)t * 128 + l * 16 + ((u & 3) << 2) + g] =
          (uint16_t)f2bf(v);
    }
  }
}

// =====================================================================
// R5 h-exchange: tags split from values to kill the L3 poll storm.
//   val[2][1024] f32 : h values, slot = step&1. Written by producers as
//     relaxed agent atomics; drained by __syncthreads' pre-barrier vmcnt(0)
//     (each wave acks its own stores at the L3 coherence point).
//   tags[2][256] u32 : one per PRODUCER WG. tid0 release-stores tag=step
//     after the drain barrier. Consumer thread tid polls ONLY tags[slot][tid]
//     (1 load/thread/sweep, sleep-throttled, decays as threads pass), then
//     one-shot reads wg tid's 4 values (2x 8B agent atomics — bypass local
//     L2, served at the same L3 serialization point the stores were acked
//     at, so no per-word tag needed), stages to LDS, barrier = all ready.
// Ring safety (2 slots) — same induction as before: publishing tag g+1
// requires having consumed ALL tags==g, each of which was published only
// after that WG fully consumed g-1. So overwriting g-1 is always safe.
// =====================================================================

// =====================================================================
// Kernel C: persistent recurrence. 256 WGs x 256 thr (1 WG/CU).
//   wave w of WG wg owns hidden unit u = wg*4+w (4 gate rows, 8 layers),
//   W_hh packed bf16x2 in 256 statically-indexed VGPRs.
// =====================================================================
__global__ __launch_bounds__(256, 1) void krnn(const float* __restrict__ Whh,
                                               const float* __restrict__ Wout,
                                               const float* __restrict__ bout,
                                               const uint16_t* __restrict__ xp,
                                               float* __restrict__ val,
                                               unsigned* __restrict__ tags,
                                               float* __restrict__ out) {
  const int tid = threadIdx.x;
  const int wg = blockIdx.x;
  const int wave = tid >> 6, lane = tid & 63;
  const int u = (wg << 2) + wave;  // this wave's hidden unit
  __shared__ float hl[2][1024];    // double buffer: consume(l) stages hl[l&1]

  // ---- pack this wave's W_hh rows into registers (fully static indexing) ----
  uint32_t w2[8][4][8];
#pragma unroll
  for (int l = 0; l < 8; ++l)
#pragma unroll
    for (int g = 0; g < 4; ++g) {
      const float* wr = &Whh[(size_t)(l * 4096 + g * 1024 + u) * 1024];
#pragma unroll
      for (int m = 0; m < 8; ++m) {
        const float f0 = wr[m * 128 + lane];
        const float f1 = wr[m * 128 + 64 + lane];
        w2[l][g][m] = f2bf(f0) | (f2bf(f1) << 16);
      }
    }

  // ---- xproj stream: lanes 0..7 hold layer=lane's 4 bf16, dbuf 1 step ahead ----
  const size_t xpb = (size_t)wg * (TSEQ * 128);
  unsigned xpx_cur = 0, xpy_cur = 0;
  if (lane < 8) {
    const uint2 v = *(const uint2*)&xp[xpb + 0 * 128 + lane * 16 + (wave << 2)];
    xpx_cur = v.x; xpy_cur = v.y;
  }

  float c = 0.f;  // cell state for unit u (redundant across lanes)
  for (int t = 0; t < TSEQ; ++t) {
    unsigned xpx_nxt = xpx_cur, xpy_nxt = xpy_cur;
    if (lane < 8) {
      const int tn = (t + 1 < TSEQ) ? (t + 1) : t;
      const uint2 v = *(const uint2*)&xp[xpb + (size_t)tn * 128 + lane * 16 + (wave << 2)];
      xpx_nxt = v.x; xpy_nxt = v.y;
    }
#pragma unroll
    for (int l = 0; l < 8; ++l) {
      const unsigned want = (unsigned)(t * 8 + l);  // state tag; slot = l&1 (== want&1)
      float* __restrict__ hbuf = hl[l & 1];

      // ---- consume: throttled 1-tag poll, then one-shot value fetch ----
      {
        const unsigned* tslot = tags + (l & 1) * 256;
        __builtin_amdgcn_s_sleep(2);  // stores are ~never visible instantly; skip a wasted sweep
        while (__hip_atomic_load(&tslot[tid], __ATOMIC_RELAXED, __HIP_MEMORY_SCOPE_AGENT) !=
               want)
          __builtin_amdgcn_s_sleep(4);  // ~107ns backoff: quiet window for stores to land
        const unsigned long long* vslot =
            (const unsigned long long*)(val + (l & 1) * 1024);
        const unsigned long long p0 =
            __hip_atomic_load(&vslot[tid * 2 + 0], __ATOMIC_RELAXED, __HIP_MEMORY_SCOPE_AGENT);
        const unsigned long long p1 =
            __hip_atomic_load(&vslot[tid * 2 + 1], __ATOMIC_RELAXED, __HIP_MEMORY_SCOPE_AGENT);
        uint4 q;
        q.x = (unsigned)p0; q.y = (unsigned)(p0 >> 32);
        q.z = (unsigned)p1; q.w = (unsigned)(p1 >> 32);
        *(uint4*)&hbuf[tid * 4] = q;  // one ds_write_b128
      }
      __syncthreads();  // B2: hbuf fully staged

      float a0 = 0.f, a1 = 0.f, a2 = 0.f, a3 = 0.f;
#pragma unroll
      for (int m = 0; m < 8; ++m) {
        const float h0 = hbuf[m * 128 + lane];
        const float h1 = hbuf[m * 128 + 64 + lane];
        const uint32_t q0 = w2[l][0][m], q1 = w2[l][1][m];
        const uint32_t q2 = w2[l][2][m], q3 = w2[l][3][m];
        a0 += bflo(q0) * h0 + bfhi(q0) * h1;
        a1 += bflo(q1) * h0 + bfhi(q1) * h1;
        a2 += bflo(q2) * h0 + bfhi(q2) * h1;
        a3 += bflo(q3) * h0 + bfhi(q3) * h1;
      }
#pragma unroll
      for (int off = 32; off > 0; off >>= 1) {  // butterfly: all lanes get full sums
        a0 += __shfl_xor(a0, off, 64);
        a1 += __shfl_xor(a1, off, 64);
        a2 += __shfl_xor(a2, off, 64);
        a3 += __shfl_xor(a3, off, 64);
      }
      const unsigned px = __shfl(xpx_cur, l, 64);  // layer l's xproj (4 bf16)
      const unsigned py = __shfl(xpy_cur, l, 64);
      const float pre_i = a0 + bflo(px);
      const float pre_f = a1 + bfhi(px);
      const float pre_g = a2 + bflo(py);
      const float pre_o = a3 + bfhi(py);
      const float ig = 1.f / (1.f + __expf(-pre_i));
      const float fg = 1.f / (1.f + __expf(-pre_f));
      const float gg = tanhf(pre_g);
      const float og = 1.f / (1.f + __expf(-pre_o));
      c = fg * c + ig * gg;
      const float hn = og * tanhf(c);

      // ---- publish h(want+1): val stores -> drain barrier -> one tag store ----
      if (lane == 0)
        __hip_atomic_store(&val[((l + 1) & 1) * 1024 + u], hn, __ATOMIC_RELAXED,
                           __HIP_MEMORY_SCOPE_AGENT);
      __syncthreads();  // B1: emits per-wave vmcnt(0) => val stores acked at L3
      if (tid == 0)
        __hip_atomic_store(&tags[((l + 1) & 1) * 256 + wg], want + 1, __ATOMIC_RELEASE,
                           __HIP_MEMORY_SCOPE_AGENT);
      // B1 also serves as "hbuf reads done" (dbuf: next consume writes other half)
    }
    xpx_cur = xpx_nxt; xpy_cur = xpy_nxt;
  }

  // ---- epilogue ----
  // sync on h-16384 tags (slot 0): proves every WG finished step 16384
  {
    const unsigned* tslot = tags;  // slot 0
    while (__hip_atomic_load(&tslot[tid], __ATOMIC_RELAXED, __HIP_MEMORY_SCOPE_AGENT) !=
           (unsigned)(TSEQ * 8))
      __builtin_amdgcn_s_sleep(4);
  }
  __syncthreads();
  // publish c as step 16385 (slot 1)
  if (lane == 0)
    __hip_atomic_store(&val[1024 + u], c, __ATOMIC_RELAXED, __HIP_MEMORY_SCOPE_AGENT);
  __syncthreads();
  if (tid == 0)
    __hip_atomic_store(&tags[256 + wg], (unsigned)(TSEQ * 8 + 1), __ATOMIC_RELEASE,
                       __HIP_MEMORY_SCOPE_AGENT);
  // consume c vector
  {
    const unsigned* tslot = tags + 256;
    while (__hip_atomic_load(&tslot[tid], __ATOMIC_RELAXED, __HIP_MEMORY_SCOPE_AGENT) !=
           (unsigned)(TSEQ * 8 + 1))
      __builtin_amdgcn_s_sleep(4);
    const unsigned long long* vslot = (const unsigned long long*)(val + 1024);
    const unsigned long long p0 =
        __hip_atomic_load(&vslot[tid * 2 + 0], __ATOMIC_RELAXED, __HIP_MEMORY_SCOPE_AGENT);
    const unsigned long long p1 =
        __hip_atomic_load(&vslot[tid * 2 + 1], __ATOMIC_RELAXED, __HIP_MEMORY_SCOPE_AGENT);
    uint4 q;
    q.x = (unsigned)p0; q.y = (unsigned)(p0 >> 32);
    q.z = (unsigned)p1; q.w = (unsigned)(p1 >> 32);
    *(uint4*)&hl[1][tid * 4] = q;
  }
  __syncthreads();

  // out[u] = c . W_out[u,:] + b_out[u]
  float s = 0.f;
  const float* wrow = &Wout[(size_t)u * 1024];
#pragma unroll
  for (int m = 0; m < 16; ++m) s += hl[1][m * 64 + lane] * wrow[m * 64 + lane];
#pragma unroll
  for (int off = 32; off > 0; off >>= 1) s += __shfl_xor(s, off, 64);
  if (lane == 0) out[u] = s + bout[u];
}

// =====================================================================
extern "C" void kernel_launch(void* const* d_in, const int* in_sizes, int n_in,
                              void* d_out, int out_size, void* d_ws, size_t ws_size,
                              hipStream_t stream) {
  (void)in_sizes; (void)n_in; (void)out_size;
  const float* x   = (const float*)d_in[0];
  const float* Wih = (const float*)d_in[1];
  const float* Whh = (const float*)d_in[2];
  const float* bih = (const float*)d_in[3];
  const float* bhh = (const float*)d_in[4];
  const float* Wou = (const float*)d_in[5];
  const float* bou = (const float*)d_in[6];
  float* out = (float*)d_out;

  const size_t XP_BYTES = (size_t)256 * TSEQ * 128 * sizeof(uint16_t);  // 128 MiB
  const size_t VAL_BYTES = 2 * 1024 * sizeof(float);                    // 8 KiB
  const size_t TAG_BYTES = 2 * 256 * sizeof(unsigned);                  // 2 KiB
  if (ws_size < XP_BYTES + VAL_BYTES + TAG_BYTES) return;  // fail visibly, don't corrupt

  uint16_t* xp = (uint16_t*)d_ws;
  float* val = (float*)((char*)d_ws + XP_BYTES);
  unsigned* tags = (unsigned*)((char*)d_ws + XP_BYTES + VAL_BYTES);

  // zeros: tags slot0 = 0 (step-0 ready), val slot0 = h0 = 0
  hipMemsetAsync(val, 0, VAL_BYTES + TAG_BYTES, stream);
  kxproj<<<dim3(32, 512), 256, 0, stream>>>(x, Wih, bih, bhh, xp);

  void* args[] = {(void*)&Whh, (void*)&Wou, (void*)&bou, (void*)&xp,
                  (void*)&val, (void*)&tags, (void*)&out};
  if (hipLaunchCooperativeKernel((const void*)krnn, dim3(256), dim3(256), args, 0, stream) !=
      hipSuccess) {
    // 256 blocks x 256 thr: 256 VGPR/lane => 1 WG/CU => co-resident; fallback ok.
    krnn<<<256, 256, 0, stream>>>(Whh, Wou, bou, xp, val, tags, out);
  }
}

// Round 10
// 87945.502 us; speedup vs baseline: 1.4951x; 1.4951x over previous
//
#include <hip/hip_runtime.h>
#include <hip/hip_bf16.h>
#include <stdint.h>

// Problem constants: H=1024, IN=1024, L=8, T=2048, OUT=1024.
// Reference quirk: EVERY layer consumes raw x_t, ONE (h,c) pair threads through
// all L*T = 16384 serial cell steps. Output = c_final @ W_out^T + b_out.
#define TSEQ 2048
#define NLAY 8

// ---- bf16 helpers (round-to-nearest-even pack, bit-shift unpack) ----
static __device__ __forceinline__ uint32_t f2bf(float f) {
  uint32_t u = __float_as_uint(f);
  return (u + 0x7FFFu + ((u >> 16) & 1u)) >> 16;
}
static __device__ __forceinline__ float bflo(uint32_t w) { return __uint_as_float(w << 16); }
static __device__ __forceinline__ float bfhi(uint32_t w) { return __uint_as_float(w & 0xFFFF0000u); }

// =====================================================================
// Kernel B: xproj = x @ W_ih^T + b_ih + b_hh  for all (t, l) — parallel GEMM
//   (unchanged since R0 — correctness proven, not the critical path)
// =====================================================================
__global__ __launch_bounds__(256) void kxproj(const float* __restrict__ x,
                                              const float* __restrict__ Wih,
                                              const float* __restrict__ bih,
                                              const float* __restrict__ bhh,
                                              uint16_t* __restrict__ xp) {
  __shared__ float xs[64][65];   // [t][k] tile (+1 pad: bank-conflict-free)
  __shared__ float wsm[64][65];  // [n][k] tile
  const int tid = threadIdx.x;
  const int tb = blockIdx.x << 6;  // t base (grid.x = 32)
  const int nb = blockIdx.y << 6;  // n base (grid.y = 512)
  const int lr = tid >> 4;         // load row 0..15
  const int lc = (tid & 15) << 2;  // load col group
  const int ty = tid >> 4;         // compute: 16x16 threads, 4x4 outputs each
  const int tx = tid & 15;
  float acc[4][4] = {};
  for (int kk = 0; kk < 1024; kk += 64) {
    __syncthreads();  // protect prior iteration's LDS reads
#pragma unroll
    for (int r4 = 0; r4 < 4; ++r4) {
      const int row = lr + (r4 << 4);
      const float4 xv4 = *(const float4*)&x[(size_t)(tb + row) * 1024 + kk + lc];
      const float4 wv4 = *(const float4*)&Wih[(size_t)(nb + row) * 1024 + kk + lc];
      xs[row][lc + 0] = xv4.x; xs[row][lc + 1] = xv4.y;
      xs[row][lc + 2] = xv4.z; xs[row][lc + 3] = xv4.w;
      wsm[row][lc + 0] = wv4.x; wsm[row][lc + 1] = wv4.y;
      wsm[row][lc + 2] = wv4.z; wsm[row][lc + 3] = wv4.w;
    }
    __syncthreads();
#pragma unroll 4
    for (int k = 0; k < 64; ++k) {
      float xv[4], wv[4];
#pragma unroll
      for (int i = 0; i < 4; ++i) xv[i] = xs[(ty << 2) + i][k];
#pragma unroll
      for (int j = 0; j < 4; ++j) wv[j] = wsm[(tx << 2) + j][k];
#pragma unroll
      for (int i = 0; i < 4; ++i)
#pragma unroll
        for (int j = 0; j < 4; ++j) acc[i][j] += xv[i] * wv[j];
    }
  }
#pragma unroll
  for (int i = 0; i < 4; ++i) {
    const int t = tb + (ty << 2) + i;
#pragma unroll
    for (int j = 0; j < 4; ++j) {
      const int n = nb + (tx << 2) + j;
      const float v = acc[i][j] + bih[n] + bhh[n];
      const int l = n >> 12;
      const int g = (n >> 10) & 3;  // 0=i 1=f 2=g 3=o (PyTorch row order)
      const int u = n & 1023;
      xp[(size_t)(u >> 2) * (TSEQ * 128) + (size_t)t * 128 + l * 16 + ((u & 3) << 2) + g] =
          (uint16_t)f2bf(v);
    }
  }
}

// =====================================================================
// R7 h-exchange — R0's fused (tag<<32|value) 8B-atomic protocol, restructured
// for line-level contention:
//   hist[slot][rep][wg] = one 128B LINE holding WG wg's 4 fused pairs
//     (slot = step&1, rep = 0..REP-1 replicas).
//   PRODUCER (wave w, lane0): right after computing hn, fire-and-forget REP
//     relaxed agent-scope 8B stores (no drain, no barrier, no release — the
//     tag travels WITH the value in one atomic).
//   CONSUMER thread tid: polls producer tid's line in replica (wg&REPMASK):
//     4 atomic loads to the same 32B issued back-to-back -> ONE waitcnt ->
//     ONE concurrent L3 RT per sweep (R0's branch-serialized 4-RT flaw fixed).
//     Readers per line = 256/REP = 32 (vs R5's 8192 on the shared tag lines).
// Ring safety (2 slots), same induction as R0 (proven): publishing tag s
// overwrites tag s-2, which is safe because publishing s requires consuming
// s-1 everywhere, which required every WG's publish of s-1 AFTER consuming
// s-2. Re-reading a ready pair is stable for the same reason.
// =====================================================================

// =====================================================================
// Kernel C: persistent recurrence. 256 WGs x 256 thr (1 WG/CU).
//   wave w of WG wg owns hidden unit u = wg*4+w (4 gate rows, 8 layers),
//   W_hh packed bf16x2 in 256 statically-indexed VGPRs.
//   Per layer-step: poll/stage h -> LDS (dbuf, ONE barrier), 64 FMA/lane dot,
//   butterfly reduce, pointwise LSTM, immediate fused publish.
// =====================================================================
__global__ __launch_bounds__(256, 1) void krnn(const float* __restrict__ Whh,
                                               const float* __restrict__ Wout,
                                               const float* __restrict__ bout,
                                               const uint16_t* __restrict__ xp,
                                               unsigned long long* __restrict__ hist,
                                               unsigned repmask,  // REP-1, REP = pow2
                                               float* __restrict__ out) {
  const int tid = threadIdx.x;
  const int wg = blockIdx.x;
  const int wave = tid >> 6, lane = tid & 63;
  const int u = (wg << 2) + wave;       // this wave's hidden unit
  const size_t slotstride = (size_t)(repmask + 1) * 4096;  // ullongs per slot
  __shared__ float hl[2][1024];         // double buffer: step l stages hl[l&1]

  // ---- pack this wave's W_hh rows into registers (fully static indexing) ----
  uint32_t w2[8][4][8];
#pragma unroll
  for (int l = 0; l < 8; ++l)
#pragma unroll
    for (int g = 0; g < 4; ++g) {
      const float* wr = &Whh[(size_t)(l * 4096 + g * 1024 + u) * 1024];
#pragma unroll
      for (int m = 0; m < 8; ++m) {
        const float f0 = wr[m * 128 + lane];
        const float f1 = wr[m * 128 + 64 + lane];
        w2[l][g][m] = f2bf(f0) | (f2bf(f1) << 16);
      }
    }

  // consumer line base offsets (within a slot), in ullongs
  const size_t rdoff = ((size_t)(wg & repmask) * 256 + (size_t)tid) * 16;

  // ---- xproj stream: lanes 0..7 hold layer=lane's 4 bf16, dbuf 1 step ahead ----
  const size_t xpb = (size_t)wg * (TSEQ * 128);
  unsigned xpx_cur = 0, xpy_cur = 0;
  if (lane < 8) {
    const uint2 v = *(const uint2*)&xp[xpb + 0 * 128 + lane * 16 + (wave << 2)];
    xpx_cur = v.x; xpy_cur = v.y;
  }

  float c = 0.f;  // cell state for unit u (redundant across lanes)
  for (int t = 0; t < TSEQ; ++t) {
    unsigned xpx_nxt = xpx_cur, xpy_nxt = xpy_cur;
    if (lane < 8) {
      const int tn = (t + 1 < TSEQ) ? (t + 1) : t;
      const uint2 v = *(const uint2*)&xp[xpb + (size_t)tn * 128 + lane * 16 + (wave << 2)];
      xpx_nxt = v.x; xpy_nxt = v.y;
    }
#pragma unroll
    for (int l = 0; l < 8; ++l) {
      const unsigned want = (unsigned)(t * 8 + l);  // consumed tag; slot = l&1
      float* __restrict__ hbuf = hl[l & 1];

      // ---- consume: 4 concurrent fused loads on ONE private line per sweep ----
      {
        const unsigned long long* ln = hist + (size_t)(l & 1) * slotstride + rdoff;
        unsigned long long v0, v1, v2, v3;
        for (;;) {
          v0 = __hip_atomic_load(&ln[0], __ATOMIC_RELAXED, __HIP_MEMORY_SCOPE_AGENT);
          v1 = __hip_atomic_load(&ln[1], __ATOMIC_RELAXED, __HIP_MEMORY_SCOPE_AGENT);
          v2 = __hip_atomic_load(&ln[2], __ATOMIC_RELAXED, __HIP_MEMORY_SCOPE_AGENT);
          v3 = __hip_atomic_load(&ln[3], __ATOMIC_RELAXED, __HIP_MEMORY_SCOPE_AGENT);
          if (((unsigned)(v0 >> 32) == want) & ((unsigned)(v1 >> 32) == want) &
              ((unsigned)(v2 >> 32) == want) & ((unsigned)(v3 >> 32) == want))
            break;
          __builtin_amdgcn_s_sleep(2);  // ~128cy backoff between sweeps
        }
        uint4 q;
        q.x = (unsigned)v0; q.y = (unsigned)v1;
        q.z = (unsigned)v2; q.w = (unsigned)v3;
        *(uint4*)&hbuf[tid * 4] = q;  // one ds_write_b128 (units tid*4..+3)
      }
      __syncthreads();  // hbuf fully staged (single barrier per layer-step)

      float a0 = 0.f, a1 = 0.f, a2 = 0.f, a3 = 0.f;
#pragma unroll
      for (int m = 0; m < 8; ++m) {
        const float h0 = hbuf[m * 128 + lane];
        const float h1 = hbuf[m * 128 + 64 + lane];
        const uint32_t q0 = w2[l][0][m], q1 = w2[l][1][m];
        const uint32_t q2 = w2[l][2][m], q3 = w2[l][3][m];
        a0 += bflo(q0) * h0 + bfhi(q0) * h1;
        a1 += bflo(q1) * h0 + bfhi(q1) * h1;
        a2 += bflo(q2) * h0 + bfhi(q2) * h1;
        a3 += bflo(q3) * h0 + bfhi(q3) * h1;
      }
#pragma unroll
      for (int off = 32; off > 0; off >>= 1) {  // butterfly: all lanes get full sums
        a0 += __shfl_xor(a0, off, 64);
        a1 += __shfl_xor(a1, off, 64);
        a2 += __shfl_xor(a2, off, 64);
        a3 += __shfl_xor(a3, off, 64);
      }
      const unsigned px = __shfl(xpx_cur, l, 64);  // layer l's xproj (4 bf16)
      const unsigned py = __shfl(xpy_cur, l, 64);
      const float pre_i = a0 + bflo(px);
      const float pre_f = a1 + bfhi(px);
      const float pre_g = a2 + bflo(py);
      const float pre_o = a3 + bfhi(py);
      const float ig = 1.f / (1.f + __expf(-pre_i));
      const float fg = 1.f / (1.f + __expf(-pre_f));
      const float gg = tanhf(pre_g);
      const float og = 1.f / (1.f + __expf(-pre_o));
      c = fg * c + ig * gg;
      const float hn = og * tanhf(c);

      // ---- publish h(want+1): immediate fire-and-forget fused stores, REP lines ----
      if (lane == 0) {
        const unsigned long long pk =
            ((unsigned long long)(want + 1) << 32) | (unsigned long long)__float_as_uint(hn);
        unsigned long long* wb = hist + (size_t)((l + 1) & 1) * slotstride + (size_t)wg * 16 + wave;
#pragma unroll 2
        for (unsigned r = 0; r <= repmask; ++r)
          __hip_atomic_store(wb + (size_t)r * 4096, pk, __ATOMIC_RELAXED,
                             __HIP_MEMORY_SCOPE_AGENT);
      }
      // no trailing barrier: dbuf + next step's post-stage barrier protect hbuf
    }
    xpx_cur = xpx_nxt; xpy_cur = xpy_nxt;
  }

  // ---- epilogue ----
  // dummy consume of tag 16384 (slot 0): proves every WG finished all steps
  {
    const unsigned long long* ln = hist + rdoff;  // slot 0
    const unsigned wantf = (unsigned)(TSEQ * 8);
    for (;;) {
      const unsigned long long v0 =
          __hip_atomic_load(&ln[0], __ATOMIC_RELAXED, __HIP_MEMORY_SCOPE_AGENT);
      const unsigned long long v1 =
          __hip_atomic_load(&ln[1], __ATOMIC_RELAXED, __HIP_MEMORY_SCOPE_AGENT);
      const unsigned long long v2 =
          __hip_atomic_load(&ln[2], __ATOMIC_RELAXED, __HIP_MEMORY_SCOPE_AGENT);
      const unsigned long long v3 =
          __hip_atomic_load(&ln[3], __ATOMIC_RELAXED, __HIP_MEMORY_SCOPE_AGENT);
      if (((unsigned)(v0 >> 32) == wantf) & ((unsigned)(v1 >> 32) == wantf) &
          ((unsigned)(v2 >> 32) == wantf) & ((unsigned)(v3 >> 32) == wantf))
        break;
      __builtin_amdgcn_s_sleep(2);
    }
  }
  __syncthreads();
  // publish c as tag 16385 (slot 1; old tags 16383 all consumed => safe)
  if (lane == 0) {
    const unsigned long long pk = ((unsigned long long)(TSEQ * 8 + 1) << 32) |
                                  (unsigned long long)__float_as_uint(c);
    unsigned long long* wb = hist + slotstride + (size_t)wg * 16 + wave;
#pragma unroll 2
    for (unsigned r = 0; r <= repmask; ++r)
      __hip_atomic_store(wb + (size_t)r * 4096, pk, __ATOMIC_RELAXED,
                         __HIP_MEMORY_SCOPE_AGENT);
  }
  // consume c vector into hl[1]
  {
    const unsigned long long* ln = hist + slotstride + rdoff;
    const unsigned wantc = (unsigned)(TSEQ * 8 + 1);
    unsigned long long v0, v1, v2, v3;
    for (;;) {
      v0 = __hip_atomic_load(&ln[0], __ATOMIC_RELAXED, __HIP_MEMORY_SCOPE_AGENT);
      v1 = __hip_atomic_load(&ln[1], __ATOMIC_RELAXED, __HIP_MEMORY_SCOPE_AGENT);
      v2 = __hip_atomic_load(&ln[2], __ATOMIC_RELAXED, __HIP_MEMORY_SCOPE_AGENT);
      v3 = __hip_atomic_load(&ln[3], __ATOMIC_RELAXED, __HIP_MEMORY_SCOPE_AGENT);
      if (((unsigned)(v0 >> 32) == wantc) & ((unsigned)(v1 >> 32) == wantc) &
          ((unsigned)(v2 >> 32) == wantc) & ((unsigned)(v3 >> 32) == wantc))
        break;
      __builtin_amdgcn_s_sleep(2);
    }
    uint4 q;
    q.x = (unsigned)v0; q.y = (unsigned)v1;
    q.z = (unsigned)v2; q.w = (unsigned)v3;
    *(uint4*)&hl[1][tid * 4] = q;
  }
  __syncthreads();

  // out[u] = c . W_out[u,:] + b_out[u]
  float s = 0.f;
  const float* wrow = &Wout[(size_t)u * 1024];
#pragma unroll
  for (int m = 0; m < 16; ++m) s += hl[1][m * 64 + lane] * wrow[m * 64 + lane];
#pragma unroll
  for (int off = 32; off > 0; off >>= 1) s += __shfl_xor(s, off, 64);
  if (lane == 0) out[u] = s + bout[u];
}

// =====================================================================
extern "C" void kernel_launch(void* const* d_in, const int* in_sizes, int n_in,
                              void* d_out, int out_size, void* d_ws, size_t ws_size,
                              hipStream_t stream) {
  (void)in_sizes; (void)n_in; (void)out_size;
  const float* x   = (const float*)d_in[0];
  const float* Wih = (const float*)d_in[1];
  const float* Whh = (const float*)d_in[2];
  const float* bih = (const float*)d_in[3];
  const float* bhh = (const float*)d_in[4];
  const float* Wou = (const float*)d_in[5];
  const float* bou = (const float*)d_in[6];
  float* out = (float*)d_out;

  const size_t XP_BYTES = (size_t)256 * TSEQ * 128 * sizeof(uint16_t);  // 128 MiB
  // hist: 2 slots x REP x 256 WGs x 128B line; REP=8 -> 512 KiB
  unsigned rep = 8;
  while (rep > 1 && ws_size < XP_BYTES + (size_t)2 * rep * 256 * 128) rep >>= 1;
  const size_t HIST_BYTES = (size_t)2 * rep * 256 * 128;
  if (ws_size < XP_BYTES + HIST_BYTES) return;  // fail visibly, don't corrupt
  const unsigned repmask = rep - 1;

  uint16_t* xp = (uint16_t*)d_ws;
  unsigned long long* hist = (unsigned long long*)((char*)d_ws + XP_BYTES);

  // zeros: slot0 tags = 0 with value h0 = 0.0f => plain zeros
  hipMemsetAsync(hist, 0, HIST_BYTES, stream);
  kxproj<<<dim3(32, 512), 256, 0, stream>>>(x, Wih, bih, bhh, xp);

  void* args[] = {(void*)&Whh, (void*)&Wou, (void*)&bou, (void*)&xp,
                  (void*)&hist, (void*)&repmask, (void*)&out};
  if (hipLaunchCooperativeKernel((const void*)krnn, dim3(256), dim3(256), args, 0, stream) !=
      hipSuccess) {
    // 256 blocks x 256 thr: 256 VGPR/lane => 1 WG/CU => co-resident; fallback ok.
    krnn<<<256, 256, 0, stream>>>(Whh, Wou, bou, xp, hist, repmask, out);
  }
}